// Round 10
// baseline (434.303 us; speedup 1.0000x reference)
//
#include <hip/hip_runtime.h>
#include <stdint.h>

#define NNODES 50000
#define NEDGES 400000
#define EMB 128
#define KD 896
#define BM 128

typedef __attribute__((ext_vector_type(8))) short bf16x8;
typedef __attribute__((ext_vector_type(4))) float f32x4;

__device__ __forceinline__ short f2bf(float f) {
  union { float f; uint32_t u; } v; v.f = f;
  uint32_t r = v.u + 0x7FFFu + ((v.u >> 16) & 1u);
  return (short)(r >> 16);
}
__device__ __forceinline__ float bf2f(short s) {
  union { uint32_t u; float f; } v; v.u = ((uint32_t)(uint16_t)s) << 16;
  return v.f;
}
__device__ __forceinline__ float fast_gelu(float x) {
  float x2 = x * x;
  float y = x * (0.7978845608f + 0.03567740814f * x2);
  float e = __expf(2.0f * y);
  float r = __builtin_amdgcn_rcpf(1.0f + e);
  return x - x * r;
}

// B layout (validated R2..R9): chunk c = sidx*4 + wn*2 + f, sidx=(i*2+fh)*4+kk
__global__ void prep_B(const float* __restrict__ W2, short* __restrict__ Bp) {
  int idx = blockIdx.x * 256 + threadIdx.x;   // 448*256 = 114688
  int m = idx & 7, l = (idx >> 3) & 63, c = idx >> 9;
  int sidx = c >> 2, wn = (c >> 1) & 1, f = c & 1;
  int p = sidx >> 2, kk = sidx & 3, i = p >> 1, fnh = p & 1;
  int o = (wn * 4 + fnh * 2 + f) * 16 + (l & 15);
  int k = kk * 32 + (l >> 4) * 8 + m;
  Bp[idx] = f2bf(W2[k * KD + i * EMB + o]);
}

// W1p: phase-1 A frags (validated R7/R9)
__global__ void prep_W1(const float* __restrict__ W1f, const float* __restrict__ b1,
                        short* __restrict__ W1p) {
  int idx = blockIdx.x * 256 + threadIdx.x;   // 16*256 = 4096
  int m = idx & 7, l = (idx >> 3) & 63, mt = idx >> 9;
  int o = mt * 16 + (l & 15), kseg = l >> 4;
  short v = 0;
  if (kseg < 2) {
    if (m < 6) v = f2bf(W1f[m * EMB + o]);
  } else if (kseg == 2) {
    if (m < 6) { float wv = W1f[m * EMB + o]; short hi = f2bf(wv); v = f2bf(wv - bf2f(hi)); }
  } else {
    if (m == 0) v = f2bf(b1[o]);
    else if (m == 1) { float bv = b1[o]; short hi = f2bf(bv); v = f2bf(bv - bf2f(hi)); }
  }
  W1p[idx] = v;
}

// ---- CSR build ----
__global__ void hist_dst(const int* __restrict__ ei, const float* __restrict__ x,
                         unsigned* __restrict__ cnt, float* __restrict__ xsum) {
  int e = blockIdx.x * 256 + threadIdx.x;
  if (e < NEDGES) {
    int d = ei[NEDGES + e];
    int s = ei[e];
    atomicAdd(&cnt[d], 1u);
#pragma unroll
    for (int i = 0; i < 7; ++i) atomicAdd(&xsum[d * 8 + i], x[s * 7 + i]);
  }
}

__global__ void scanA(const unsigned* __restrict__ cnt, unsigned* __restrict__ woff,
                      unsigned* __restrict__ part) {
  __shared__ unsigned ps[256];
  int t = threadIdx.x, n = blockIdx.x * 256 + t;
  unsigned v = (n < NNODES) ? cnt[n] : 0u;
  ps[t] = v; __syncthreads();
  for (int d = 1; d < 256; d <<= 1) {
    unsigned u = (t >= d) ? ps[t - d] : 0u;
    __syncthreads(); ps[t] += u; __syncthreads();
  }
  if (n < NNODES) woff[n] = ps[t] - v;       // block-local exclusive
  if (t == 255) part[blockIdx.x] = ps[t];
}

__global__ void scanB(unsigned* __restrict__ part) {
  __shared__ unsigned ps[256];
  int t = threadIdx.x;
  unsigned v = (t < 196) ? part[t] : 0u;
  ps[t] = v; __syncthreads();
  for (int d = 1; d < 256; d <<= 1) {
    unsigned u = (t >= d) ? ps[t - d] : 0u;
    __syncthreads(); ps[t] += u; __syncthreads();
  }
  if (t < 196) part[t] = ps[t] - v;          // exclusive
}

__global__ void scanC(unsigned* __restrict__ woff, const unsigned* __restrict__ part) {
  int n = blockIdx.x * 256 + threadIdx.x;
  if (n < NNODES) woff[n] += part[blockIdx.x];
}

__global__ void scatter_e(const int* __restrict__ ei, unsigned* __restrict__ woff,
                          unsigned* __restrict__ eord, int* __restrict__ dsts,
                          int* __restrict__ srcs) {
  int e = blockIdx.x * 256 + threadIdx.x;
  if (e < NEDGES) {
    int d = ei[NEDGES + e];
    unsigned p = atomicAdd(&woff[d], 1u);
    eord[p] = (unsigned)e;
    dsts[p] = d;
    srcs[p] = ei[e];
  }
}

__global__ __launch_bounds__(256, 2)
void nnconv_main(const float* __restrict__ x,
                 const float* __restrict__ ea,
                 const short* __restrict__ Bp,
                 const short* __restrict__ W1p,
                 const unsigned* __restrict__ eord,
                 const int* __restrict__ dsts,
                 const int* __restrict__ srcs,
                 float* __restrict__ out) {
  __shared__ __align__(16) char smem[33280];      // h_s (32KB bf16) / red_s[128][65] f32
  short* h_s = (short*)smem;
  float* red_s = (float*)smem;
  __shared__ __align__(16) float x_t[7][132];
  __shared__ __align__(16) float ea_s[BM * 6];
  __shared__ int dst_s[BM + 4];

  const int t = threadIdx.x;
  const int lane = t & 63;
  const int w = t >> 6;
  const int wm = w >> 1, wn = w & 1;
  const int rowA = lane & 15;
  const int kseg = lane >> 4;
  const int eb = blockIdx.x * BM;
  const char* BpB = (const char*)Bp + wn * 2048 + lane * 16;

  bf16x8 bufA[4][2], bufB[4][2];
#pragma unroll
  for (int kk = 0; kk < 4; ++kk)
#pragma unroll
    for (int f = 0; f < 2; ++f)
      bufA[kk][f] = *(const bf16x8*)(BpB + (((size_t)kk * 4 + f) << 10));

  // ---- phase 0: coalesced sorted dst/src; x gather (L2); ea via eord ----
  if (t < BM) {
    const int s = srcs[eb + t];
    dst_s[t] = dsts[eb + t];
#pragma unroll
    for (int i = 0; i < 7; ++i) x_t[i][t] = x[s * 7 + i];
    const int e = (int)eord[eb + t];
#pragma unroll
    for (int q = 0; q < 6; ++q) ea_s[t * 6 + q] = ea[(size_t)e * 6 + q];
  }
  if (t == BM) dst_s[BM] = -1;
  __syncthreads();

  // ---- phase 1: h = gelu(ea@W1+b1) via MFMA -> swizzled h_s ----
  {
    bf16x8 wa[8];
#pragma unroll
    for (int mt = 0; mt < 8; ++mt)
      wa[mt] = *(const bf16x8*)(W1p + (mt * 64 + lane) * 8);
#pragma unroll
    for (int et2 = 0; et2 < 2; ++et2) {
      const int e = w * 32 + et2 * 16 + rowA;
      bf16x8 be = (bf16x8){0, 0, 0, 0, 0, 0, 0, 0};
      if (kseg == 3) {
        be[0] = f2bf(1.0f); be[1] = f2bf(1.0f);
      } else {
#pragma unroll
        for (int q = 0; q < 6; ++q) {
          float v = ea_s[e * 6 + q];
          short hi = f2bf(v);
          be[q] = (kseg == 1) ? f2bf(v - bf2f(hi)) : hi;
        }
      }
      const int swz = (e & 15) << 4;
#pragma unroll
      for (int mt = 0; mt < 8; ++mt) {
        f32x4 d = __builtin_amdgcn_mfma_f32_16x16x32_bf16(
            wa[mt], be, (f32x4){0.f, 0.f, 0.f, 0.f}, 0, 0, 0);
        uint32_t h0 = (uint16_t)f2bf(fast_gelu(d[0]));
        uint32_t h1 = (uint16_t)f2bf(fast_gelu(d[1]));
        uint32_t h2 = (uint16_t)f2bf(fast_gelu(d[2]));
        uint32_t h3 = (uint16_t)f2bf(fast_gelu(d[3]));
        uint2 u; u.x = h0 | (h1 << 16); u.y = h2 | (h3 << 16);
        int off = (mt * 32 + kseg * 8) ^ swz;
        *(uint2*)((char*)h_s + e * 256 + off) = u;
      }
    }
  }
  __syncthreads();

  // ---- A fragments once (i-invariant) ----
  bf16x8 A[4][4];
#pragma unroll
  for (int kk = 0; kk < 4; ++kk)
#pragma unroll
    for (int fm = 0; fm < 4; ++fm) {
      int row = wm * 64 + fm * 16 + rowA;
      int off = (kk * 64 + kseg * 16) ^ (rowA << 4);
      A[kk][fm] = *(const bf16x8*)((const char*)h_s + row * 256 + off);
    }

  // one i-step: consume BC, prefetch next chunk-set into BN (dist = 64 MFMAs)
#define ISTEP(BC, BN, NS, II)                                                        \
  do {                                                                               \
    _Pragma("unroll")                                                                \
    for (int kk = 0; kk < 4; ++kk) {                                                 \
      BN[kk][0] = *(const bf16x8*)(BpB + (((size_t)((NS) + kk) * 4 + 0) << 10));     \
      BN[kk][1] = *(const bf16x8*)(BpB + (((size_t)((NS) + kk) * 4 + 1) << 10));     \
    }                                                                                \
    f32x4 tmp[4][2];                                                                 \
    _Pragma("unroll")                                                                \
    for (int a = 0; a < 4; ++a) {                                                    \
      tmp[a][0] = (f32x4){0.f, 0.f, 0.f, 0.f};                                       \
      tmp[a][1] = (f32x4){0.f, 0.f, 0.f, 0.f};                                       \
    }                                                                                \
    _Pragma("unroll")                                                                \
    for (int kk = 0; kk < 4; ++kk)                                                   \
      _Pragma("unroll")                                                              \
      for (int fm = 0; fm < 4; ++fm) {                                               \
        tmp[fm][0] = __builtin_amdgcn_mfma_f32_16x16x32_bf16(A[kk][fm], BC[kk][0],   \
                                                             tmp[fm][0], 0, 0, 0);   \
        tmp[fm][1] = __builtin_amdgcn_mfma_f32_16x16x32_bf16(A[kk][fm], BC[kk][1],   \
                                                             tmp[fm][1], 0, 0, 0);   \
      }                                                                              \
    _Pragma("unroll")                                                                \
    for (int fm = 0; fm < 4; ++fm) {                                                 \
      f32x4 xv = *(const f32x4*)&x_t[II][wm * 64 + fm * 16 + kseg * 4];              \
      _Pragma("unroll")                                                              \
      for (int r = 0; r < 4; ++r) {                                                  \
        acc2[fm][0][r] += xv[r] * tmp[fm][0][r];                                     \
        acc2[fm][1][r] += xv[r] * tmp[fm][1][r];                                     \
      }                                                                              \
    }                                                                                \
  } while (0)

#define NS0(II) ((II) < 6 ? ((II) + 1) * 8 : 4)
#define NS1(II) ((II) < 6 ? ((II) + 1) * 8 + 4 : 52)

#define EPILOG(FH)                                                                   \
  do {                                                                               \
    __syncthreads();                                                                 \
    _Pragma("unroll")                                                                \
    for (int fm = 0; fm < 4; ++fm)                                                   \
      _Pragma("unroll")                                                              \
      for (int r = 0; r < 4; ++r) {                                                  \
        const int row = wm * 64 + fm * 16 + kseg * 4 + r;                            \
        red_s[row * 65 + wn * 32 + rowA]      = acc2[fm][0][r];                      \
        red_s[row * 65 + wn * 32 + 16 + rowA] = acc2[fm][1][r];                      \
      }                                                                              \
    __syncthreads();                                                                 \
    {                                                                                \
      const int gcol = (FH) * 32 + (lane & 31) + (lane >> 5) * 64;                   \
      const int base = w * 32;                                                       \
      float run = 0.f;                                                               \
      int runstart = 0;                                                              \
      for (int j = 0; j < 32; ++j) {                                                 \
        run += red_s[(base + j) * 65 + lane];                                        \
        const int d = dst_s[base + j];                                               \
        const bool endrun = (j == 31) || (dst_s[base + j + 1] != d);                 \
        if (endrun) {                                                                \
          float* op = out + (size_t)d * EMB + gcol;                                  \
          if (runstart > 0 && j < 31) *op = run;                                     \
          else atomicAdd(op, run);                                                   \
          run = 0.f;                                                                 \
          runstart = j + 1;                                                          \
        }                                                                            \
      }                                                                              \
    }                                                                                \
  } while (0)

  f32x4 acc2[4][2];
  // ---- fh = 0 (starts on bufA) ----
#pragma unroll
  for (int a = 0; a < 4; ++a) { acc2[a][0] = (f32x4){0,0,0,0}; acc2[a][1] = (f32x4){0,0,0,0}; }
  ISTEP(bufA, bufB, NS0(0), 0);
  ISTEP(bufB, bufA, NS0(1), 1);
  ISTEP(bufA, bufB, NS0(2), 2);
  ISTEP(bufB, bufA, NS0(3), 3);
  ISTEP(bufA, bufB, NS0(4), 4);
  ISTEP(bufB, bufA, NS0(5), 5);
  ISTEP(bufA, bufB, NS0(6), 6);     // loads (fh=1,i=0) into bufB
  EPILOG(0);

  // ---- fh = 1 (starts on bufB) ----
#pragma unroll
  for (int a = 0; a < 4; ++a) { acc2[a][0] = (f32x4){0,0,0,0}; acc2[a][1] = (f32x4){0,0,0,0}; }
  ISTEP(bufB, bufA, NS1(0), 0);
  ISTEP(bufA, bufB, NS1(1), 1);
  ISTEP(bufB, bufA, NS1(2), 2);
  ISTEP(bufA, bufB, NS1(3), 3);
  ISTEP(bufB, bufA, NS1(4), 4);
  ISTEP(bufA, bufB, NS1(5), 5);
  ISTEP(bufB, bufA, NS1(6), 6);     // dummy prefetch (clamped, dead)
  EPILOG(1);
}

// out = (out + xsum·b2)/clip(cnt,1) + x@root + bias
__global__ void finalize(const float* __restrict__ x, const float* __restrict__ root,
                         const float* __restrict__ bias, const float* __restrict__ b2,
                         const unsigned* __restrict__ cnt, const float* __restrict__ xsum,
                         float* __restrict__ out) {
  int idx = blockIdx.x * 256 + threadIdx.x;
  int n = idx >> 7, o = idx & 127;
  float c = fmaxf((float)cnt[n], 1.0f);
  float s = out[idx];
#pragma unroll
  for (int i = 0; i < 7; ++i) s += xsum[n * 8 + i] * b2[i * EMB + o];
  float v = s / c + bias[o];
#pragma unroll
  for (int i = 0; i < 7; ++i) v += x[n * 7 + i] * root[i * EMB + o];
  out[idx] = v;
}

extern "C" void kernel_launch(void* const* d_in, const int* in_sizes, int n_in,
                              void* d_out, int out_size, void* d_ws, size_t ws_size,
                              hipStream_t stream) {
  const float* x    = (const float*)d_in[0];
  const int*   ei   = (const int*)d_in[1];
  const float* ea   = (const float*)d_in[2];
  const float* W1   = (const float*)d_in[3];
  const float* b1   = (const float*)d_in[4];
  const float* W2   = (const float*)d_in[5];
  const float* b2   = (const float*)d_in[6];
  const float* root = (const float*)d_in[7];
  const float* bias = (const float*)d_in[8];
  float* out = (float*)d_out;

  char* ws = (char*)d_ws;
  short*    Bp    = (short*)ws;                         // 229376
  short*    W1p   = (short*)(ws + 229376);              // 8192
  unsigned* cnt_u = (unsigned*)(ws + 237568);           // 200000
  float*    xsum  = (float*)(ws + 437568);              // 1600000
  unsigned* woff  = (unsigned*)(ws + 2037568);          // 200000
  unsigned* part  = (unsigned*)(ws + 2237568);          // 1024
  unsigned* eord  = (unsigned*)(ws + 2238592);          // 1600000
  int*      dsts  = (int*)(ws + 3838592);               // 1600000
  int*      srcs  = (int*)(ws + 5438592);               // 1600000 (end 7038592)

  hipMemsetAsync(out, 0, (size_t)NNODES * EMB * sizeof(float), stream);
  hipMemsetAsync(cnt_u, 0, 1800000, stream);            // cnt + xsum contiguous
  prep_B<<<448, 256, 0, stream>>>(W2, Bp);
  prep_W1<<<16, 256, 0, stream>>>(W1, b1, W1p);
  hist_dst<<<(NEDGES + 255) / 256, 256, 0, stream>>>(ei, x, cnt_u, xsum);
  scanA<<<196, 256, 0, stream>>>(cnt_u, woff, part);
  scanB<<<1, 256, 0, stream>>>(part);
  scanC<<<196, 256, 0, stream>>>(woff, part);
  scatter_e<<<(NEDGES + 255) / 256, 256, 0, stream>>>(ei, woff, eord, dsts, srcs);
  nnconv_main<<<NEDGES / BM, 256, 0, stream>>>(x, ea, Bp, W1p, eord, dsts, srcs, out);
  finalize<<<NNODES * EMB / 256, 256, 0, stream>>>(x, root, bias, b2, cnt_u, xsum, out);
}